// Round 1
// 335.978 us; speedup vs baseline: 1.1332x; 1.1332x over previous
//
#include <hip/hip_runtime.h>
#include <math.h>

// Problem constants (from setup_inputs): B=4, S=2048, D=4096, 2B*S = 16384 rows.
#define PAD_ID 50256
#define S_LEN 2048
#define B_PAIRS 4
#define D4_C 1024          // D/4 = 4096/4
#define ROWS_PER_WAVE 2    // each wave computes 2 rows, reusing w-in-registers

// clang ext vector so __builtin_nontemporal_load works (HIP float4 is a struct).
typedef float fvec4 __attribute__((ext_vector_type(4)));

// ---------------------------------------------------------------------------
// Kernel 1: rewards[row] = dot(hidden_states[row,:], w)
// 256-thread blocks (4 waves); each wave handles ROWS_PER_WAVE consecutive
// rows. w is hoisted into 16 float4 registers per lane. Inner loop is a pure
// hs stream: 16 coalesced 16B loads per row, fully unrolled, 2 accumulators.
// hs is read EXACTLY ONCE (268 MB, no reuse) -> nontemporal loads to skip
// cache fill and keep rew/w/ids hot in L2 for kernel 2.
// Also zeroes out[0] (loss accumulator slot) so kernel 2 can atomicAdd into it
// (stream ordering guarantees visibility before scores_kernel starts).
// ---------------------------------------------------------------------------
__global__ __launch_bounds__(256) void rewards_kernel(
    const fvec4* __restrict__ hs,    // (nrows, D/4) as float4
    const fvec4* __restrict__ w4,    // (D/4,)
    float* __restrict__ out,         // out[0]=loss slot, out+1 = rewards
    int nrows)
{
    if (blockIdx.x == 0 && threadIdx.x == 0) out[0] = 0.0f;
    float* __restrict__ rew = out + 1;

    const int wave = threadIdx.x >> 6;
    const int lane = threadIdx.x & 63;
    const int row0 = (blockIdx.x * 4 + wave) * ROWS_PER_WAVE;

    // Hoist w into registers: lane holds w4[lane + 64k], k = 0..15 (64 VGPRs).
    fvec4 wv[16];
    #pragma unroll
    for (int k = 0; k < 16; ++k)
        wv[k] = w4[lane + 64 * k];

    #pragma unroll
    for (int r = 0; r < ROWS_PER_WAVE; ++r) {
        const int row = row0 + r;
        if (row >= nrows) return;
        const fvec4* rp = hs + (size_t)row * D4_C;

        float acc0 = 0.0f, acc1 = 0.0f;
        #pragma unroll
        for (int k = 0; k < 16; k += 2) {
            fvec4 a0 = __builtin_nontemporal_load(rp + lane + 64 * k);
            fvec4 a1 = __builtin_nontemporal_load(rp + lane + 64 * (k + 1));
            acc0 = fmaf(a0.x, wv[k].x, acc0);
            acc0 = fmaf(a0.y, wv[k].y, acc0);
            acc0 = fmaf(a0.z, wv[k].z, acc0);
            acc0 = fmaf(a0.w, wv[k].w, acc0);
            acc1 = fmaf(a1.x, wv[k + 1].x, acc1);
            acc1 = fmaf(a1.y, wv[k + 1].y, acc1);
            acc1 = fmaf(a1.z, wv[k + 1].z, acc1);
            acc1 = fmaf(a1.w, wv[k + 1].w, acc1);
        }
        float acc = acc0 + acc1;

        // wave-64 butterfly reduce
        #pragma unroll
        for (int off = 32; off > 0; off >>= 1)
            acc += __shfl_down(acc, off, 64);
        if (lane == 0) rew[row] = acc;
    }
}

// ---------------------------------------------------------------------------
// Kernel 2: per-pair indices, masked means, end scores, pairwise loss.
// One 1024-thread block PER PAIR (grid = 4): the 4 pairs run in parallel on
// 4 CUs instead of serially on one. Per-pair loss is combined into out[0] via
// device-scope atomicAdd (out[0] pre-zeroed by kernel 1; float-add ordering
// nondeterminism ~1e-7, far under the 3.9e-3 tolerance).
// Output layout: out[0]=loss, out[1..16384]=rewards (written by kernel 1),
// out[16385+ b]=chosen_mean, +4 rejected_mean, +8 chosen_end, +12 rejected_end.
// ---------------------------------------------------------------------------
__device__ inline float wave_sum(float v) {
    #pragma unroll
    for (int off = 32; off > 0; off >>= 1) v += __shfl_down(v, off, 64);
    return v;
}
__device__ inline int wave_min(int v) {
    #pragma unroll
    for (int off = 32; off > 0; off >>= 1) v = min(v, __shfl_down(v, off, 64));
    return v;
}

__global__ __launch_bounds__(1024) void scores_kernel(
    const float* __restrict__ rew,   // (2B, S) == out + 1
    const int*   __restrict__ ids,   // (2B, S) int32 (JAX x64 disabled)
    float* __restrict__ out)
{
    __shared__ int   si[3][16];
    __shared__ float sf[3][16];
    __shared__ int   s_div, s_end;

    const int b    = blockIdx.x;          // pair index 0..3
    const int tid  = threadIdx.x;
    const int lane = tid & 63;
    const int wave = tid >> 6;            // 0..15

    const int*   ch = ids + (size_t)b * S_LEN;
    const int*   rj = ids + (size_t)(B_PAIRS + b) * S_LEN;
    const float* cr = rew + (size_t)b * S_LEN;
    const float* rr = rew + (size_t)(B_PAIRS + b) * S_LEN;

    // --- first-index scans (2 strided iterations per thread) ---
    int ldiv = S_LEN, lc = S_LEN, lr = S_LEN;
    for (int s = tid; s < S_LEN; s += 1024) {
        int c = ch[s], r = rj[s];
        if (c != r)      ldiv = min(ldiv, s);
        if (c == PAD_ID) lc   = min(lc, s);
        if (r == PAD_ID) lr   = min(lr, s);
    }
    ldiv = wave_min(ldiv); lc = wave_min(lc); lr = wave_min(lr);
    if (lane == 0) { si[0][wave] = ldiv; si[1][wave] = lc; si[2][wave] = lr; }
    __syncthreads();
    if (tid == 0) {
        int dv = S_LEN, ci = S_LEN, ri = S_LEN;
        #pragma unroll
        for (int w = 0; w < 16; ++w) {
            dv = min(dv, si[0][w]);
            ci = min(ci, si[1][w]);
            ri = min(ri, si[2][w]);
        }
        s_div = dv;
        s_end = max(ci, ri);
    }
    __syncthreads();
    const int dv = s_div, en = s_end;

    // --- masked sums over [dv, en) ---
    float sc = 0.0f, sr = 0.0f, sl = 0.0f;
    for (int s = dv + tid; s < en; s += 1024) {
        float cv = cr[s], rv = rr[s];
        sc += cv;
        sr += rv;
        float x = cv - rv;
        // -log_sigmoid(x) = softplus(-x), numerically stable form:
        sl += fmaxf(-x, 0.0f) + log1pf(expf(-fabsf(x)));
    }
    sc = wave_sum(sc); sr = wave_sum(sr); sl = wave_sum(sl);
    if (lane == 0) { sf[0][wave] = sc; sf[1][wave] = sr; sf[2][wave] = sl; }
    __syncthreads();
    if (tid == 0) {
        float tsc = 0.0f, tsr = 0.0f, tsl = 0.0f;
        #pragma unroll
        for (int w = 0; w < 16; ++w) {
            tsc += sf[0][w]; tsr += sf[1][w]; tsl += sf[2][w];
        }
        int cnt_i = en - dv;
        if (cnt_i < 1) cnt_i = 1;
        float inv_cnt = 1.0f / (float)cnt_i;
        int last = en - 1;
        if (last < 0) last = 0;
        const int base = 1 + 2 * B_PAIRS * S_LEN;   // 1 + 16384
        out[base + 0 * B_PAIRS + b] = tsc * inv_cnt;  // chosen_mean_scores
        out[base + 1 * B_PAIRS + b] = tsr * inv_cnt;  // rejected_mean_scores
        out[base + 2 * B_PAIRS + b] = cr[last];       // chosen_end_scores
        out[base + 3 * B_PAIRS + b] = rr[last];       // rejected_end_scores
        atomicAdd(out, tsl * inv_cnt * (1.0f / (float)B_PAIRS));
    }
}

extern "C" void kernel_launch(void* const* d_in, const int* in_sizes, int n_in,
                              void* d_out, int out_size, void* d_ws, size_t ws_size,
                              hipStream_t stream) {
    const float* hs  = (const float*)d_in[0];   // (2B, S, D) fp32
    const float* w   = (const float*)d_in[1];   // (D,) fp32
    const int*   ids = (const int*)d_in[2];     // (2B, S) int32

    float* out = (float*)d_out;
    float* rew = out + 1;                       // rewards live at out[1..16384]

    const int nrows = in_sizes[0] / in_sizes[1];   // 16384

    // Kernel 1: GEMV rewards (memory-bound, ~268 MB stream) + zero loss slot
    const int rows_per_block = 4 * ROWS_PER_WAVE;  // 8
    const int blocks = (nrows + rows_per_block - 1) / rows_per_block;
    rewards_kernel<<<blocks, 256, 0, stream>>>(
        (const fvec4*)hs, (const fvec4*)w, out, nrows);

    // Kernel 2: one block per pair, parallel indices + means + ends + loss
    scores_kernel<<<B_PAIRS, 1024, 0, stream>>>(rew, ids, out);
}